// Round 6
// baseline (430.419 us; speedup 1.0000x reference)
//
#include <hip/hip_runtime.h>
#include <hip/hip_bf16.h>
#include <math.h>

typedef __hip_bfloat16 bf16;
typedef __attribute__((ext_vector_type(8))) short short8;
typedef __attribute__((ext_vector_type(4))) short short4v;
typedef __attribute__((ext_vector_type(4))) float floatx4;

#define D_MODEL 1024
#define SEQ     2048
#define BATCH   2
#define NHEAD   16
#define HDIM    64
#define FFDIM   4096
#define ROWS    (BATCH*SEQ)   // 4096 token rows

__device__ __forceinline__ void stv(bf16* p, float v)  { *p = __float2bfloat16(v); }
__device__ __forceinline__ void stv(float* p, float v) { *p = v; }

__device__ __forceinline__ void load_lds16(const bf16* g, bf16* l) {
  __builtin_amdgcn_global_load_lds((const __attribute__((address_space(1))) void*)g,
                                   (__attribute__((address_space(3))) void*)l, 16, 0, 0);
}

// ---------------- LayerNorm: one 256-thread block per row of 1024 ----------------
template<typename IN_T>
__global__ void ln_kernel(const IN_T* __restrict__ x, const float* __restrict__ g,
                          const float* __restrict__ beta, bf16* __restrict__ out) {
  const int row = blockIdx.x;
  const int tid = threadIdx.x;
  __shared__ float red[8];
  const IN_T* xr = x + (size_t)row * D_MODEL;
  float v[4], s = 0.f, ss = 0.f;
#pragma unroll
  for (int i = 0; i < 4; i++) {
    float val = (float)xr[tid + i * 256];
    v[i] = val; s += val; ss += val * val;
  }
#pragma unroll
  for (int off = 32; off > 0; off >>= 1) {
    s  += __shfl_down(s, off);
    ss += __shfl_down(ss, off);
  }
  if ((tid & 63) == 0) { red[tid >> 6] = s; red[4 + (tid >> 6)] = ss; }
  __syncthreads();
  s  = red[0] + red[1] + red[2] + red[3];
  ss = red[4] + red[5] + red[6] + red[7];
  const float mu  = s * (1.0f / D_MODEL);
  const float var = ss * (1.0f / D_MODEL) - mu * mu;
  const float rs  = rsqrtf(var + 1e-5f);
  bf16* orow = out + (size_t)row * D_MODEL;
#pragma unroll
  for (int i = 0; i < 4; i++) {
    int c = tid + i * 256;
    stv(orow + c, (v[i] - mu) * rs * g[c] + beta[c]);
  }
}

// ---------------- W[K][N] f32 -> Wt[N][K] bf16 (transpose + cast) ----------------
__global__ __launch_bounds__(256) void convert_w(const float* __restrict__ W,
                                                 bf16* __restrict__ Wt, int K, int N) {
  __shared__ float tile[64][65];
  const int n0 = blockIdx.x * 64, k0 = blockIdx.y * 64;
  const int tid = threadIdx.x;
  const int r = tid >> 2, c0 = (tid & 3) * 16;
#pragma unroll
  for (int j = 0; j < 16; j += 4) {
    float4 v = *(const float4*)&W[(size_t)(k0 + r) * N + n0 + c0 + j];
    tile[r][c0 + j]     = v.x; tile[r][c0 + j + 1] = v.y;
    tile[r][c0 + j + 2] = v.z; tile[r][c0 + j + 3] = v.w;
  }
  __syncthreads();
  bf16 ov[16];
#pragma unroll
  for (int j = 0; j < 16; j++) ov[j] = __float2bfloat16(tile[c0 + j][r]);
  *(short8*)&Wt[(size_t)(n0 + r) * K + k0 + c0]     = *(const short8*)&ov[0];
  *(short8*)&Wt[(size_t)(n0 + r) * K + k0 + c0 + 8] = *(const short8*)&ov[8];
}

// ------------- V-transpose: vT[h*64+d][b*2048+t] = qkv[b*2048+t][2048+h*64+d] ----
__global__ __launch_bounds__(256) void v_transpose(const bf16* __restrict__ qkv,
                                                   bf16* __restrict__ vT) {
  __shared__ bf16 tile[64][72];
  const int m0 = blockIdx.x * 64;     // token tile
  const int d0 = blockIdx.y * 64;     // head-dim tile
  const int tid = threadIdx.x;
  const int r = tid >> 2, c0 = (tid & 3) * 16;
  *(short8*)&tile[r][c0]     = *(const short8*)&qkv[(size_t)(m0 + r) * 3072 + 2048 + d0 + c0];
  *(short8*)&tile[r][c0 + 8] = *(const short8*)&qkv[(size_t)(m0 + r) * 3072 + 2048 + d0 + c0 + 8];
  __syncthreads();
  bf16 ov[16];
#pragma unroll
  for (int j = 0; j < 16; j++) ov[j] = tile[c0 + j][r];
  *(short8*)&vT[(size_t)(d0 + r) * (size_t)ROWS + m0 + c0]     = *(const short8*)&ov[0];
  *(short8*)&vT[(size_t)(d0 + r) * (size_t)ROWS + m0 + c0 + 8] = *(const short8*)&ov[8];
}

// ---------------- MFMA GEMM: C[M,N] = act(A[M,K] @ Bt[N,K]^T + bias) ------------
template<int ACT, typename OUT_T>
__global__ __launch_bounds__(256) void gemm_mfma(
    const bf16* __restrict__ A, const bf16* __restrict__ Bt,
    const float* __restrict__ bias, OUT_T* __restrict__ C, int M, int N, int K) {
  __shared__ __align__(16) bf16 As[128][64];
  __shared__ __align__(16) bf16 Bs[128][64];
  const int tid = threadIdx.x;
  const int w = tid >> 6, lane = tid & 63;
  const int quad = lane >> 4, l16 = lane & 15;
  const int wm = w >> 1, wn = w & 1;
  const int m0 = blockIdx.y * 128, n0 = blockIdx.x * 128;
  const int rb = lane >> 3, cb = lane & 7;
  const int csw = cb ^ rb;

  const bf16* Ag = A  + (size_t)(m0 + w * 8 + rb) * K + csw * 8;
  const bf16* Bg = Bt + (size_t)(n0 + w * 8 + rb) * K + csw * 8;

  floatx4 acc[4][4];
#pragma unroll
  for (int i = 0; i < 4; i++)
#pragma unroll
    for (int j = 0; j < 4; j++) acc[i][j] = (floatx4){0.f, 0.f, 0.f, 0.f};

  const int sw = l16 & 7;
  for (int k0 = 0; k0 < K; k0 += 64) {
    __syncthreads();
#pragma unroll
    for (int j = 0; j < 4; j++) {
      load_lds16(Ag + k0 + (size_t)j * 32 * K, &As[j * 32 + w * 8][0]);
      load_lds16(Bg + k0 + (size_t)j * 32 * K, &Bs[j * 32 + w * 8][0]);
    }
    __syncthreads();
    short8 af[4][2], bfr[4][2];
#pragma unroll
    for (int t = 0; t < 4; t++) {
#pragma unroll
      for (int hh = 0; hh < 2; hh++) {
        int cc = ((quad + hh * 4) ^ sw) * 8;
        af[t][hh]  = *(const short8*)&As[wm * 64 + t * 16 + l16][cc];
        bfr[t][hh] = *(const short8*)&Bs[wn * 64 + t * 16 + l16][cc];
      }
    }
#pragma unroll
    for (int mt = 0; mt < 4; mt++)
#pragma unroll
      for (int nt = 0; nt < 4; nt++) {
        acc[mt][nt] = __builtin_amdgcn_mfma_f32_16x16x32_bf16(af[mt][0], bfr[nt][0], acc[mt][nt], 0, 0, 0);
        acc[mt][nt] = __builtin_amdgcn_mfma_f32_16x16x32_bf16(af[mt][1], bfr[nt][1], acc[mt][nt], 0, 0, 0);
      }
  }

  const int mbase = m0 + wm * 64 + quad * 4;
  const int nbase = n0 + wn * 64 + l16;
  float bv[4];
#pragma unroll
  for (int nt = 0; nt < 4; nt++) bv[nt] = bias[nbase + nt * 16];
#pragma unroll
  for (int mt = 0; mt < 4; mt++) {
#pragma unroll
    for (int r = 0; r < 4; r++) {
      const int m = mbase + mt * 16 + r;
#pragma unroll
      for (int nt = 0; nt < 4; nt++) {
        const int n = nbase + nt * 16;
        float val = acc[mt][nt][r] + bv[nt];
        if (ACT == 1) val = 0.5f * val * (1.0f + erff(val * 0.70710678118f));
        stv(&C[(size_t)m * N + n], val);
      }
    }
  }
}

// -------- Split-K MFMA GEMM: C (pre-zeroed f32) += A@Bt^T (+ bias + res on z=0) --
// blockIdx.z = K-chunk. Combines via device-scope atomicAdd (distinct addrs).
__global__ __launch_bounds__(256) void gemm_mfma_sk(
    const bf16* __restrict__ A, const bf16* __restrict__ Bt,
    const float* __restrict__ bias, const float* __restrict__ res,
    float* __restrict__ C, int M, int N, int K, int KC) {
  __shared__ __align__(16) bf16 As[128][64];
  __shared__ __align__(16) bf16 Bs[128][64];
  const int tid = threadIdx.x;
  const int w = tid >> 6, lane = tid & 63;
  const int quad = lane >> 4, l16 = lane & 15;
  const int wm = w >> 1, wn = w & 1;
  const int m0 = blockIdx.y * 128, n0 = blockIdx.x * 128;
  const int kc = blockIdx.z;
  const int rb = lane >> 3, cb = lane & 7;
  const int csw = cb ^ rb;

  const bf16* Ag = A  + (size_t)(m0 + w * 8 + rb) * K + csw * 8;
  const bf16* Bg = Bt + (size_t)(n0 + w * 8 + rb) * K + csw * 8;

  floatx4 acc[4][4];
#pragma unroll
  for (int i = 0; i < 4; i++)
#pragma unroll
    for (int j = 0; j < 4; j++) acc[i][j] = (floatx4){0.f, 0.f, 0.f, 0.f};

  const int sw = l16 & 7;
  const int kend = kc * KC + KC;
  for (int k0 = kc * KC; k0 < kend; k0 += 64) {
    __syncthreads();
#pragma unroll
    for (int j = 0; j < 4; j++) {
      load_lds16(Ag + k0 + (size_t)j * 32 * K, &As[j * 32 + w * 8][0]);
      load_lds16(Bg + k0 + (size_t)j * 32 * K, &Bs[j * 32 + w * 8][0]);
    }
    __syncthreads();
    short8 af[4][2], bfr[4][2];
#pragma unroll
    for (int t = 0; t < 4; t++) {
#pragma unroll
      for (int hh = 0; hh < 2; hh++) {
        int cc = ((quad + hh * 4) ^ sw) * 8;
        af[t][hh]  = *(const short8*)&As[wm * 64 + t * 16 + l16][cc];
        bfr[t][hh] = *(const short8*)&Bs[wn * 64 + t * 16 + l16][cc];
      }
    }
#pragma unroll
    for (int mt = 0; mt < 4; mt++)
#pragma unroll
      for (int nt = 0; nt < 4; nt++) {
        acc[mt][nt] = __builtin_amdgcn_mfma_f32_16x16x32_bf16(af[mt][0], bfr[nt][0], acc[mt][nt], 0, 0, 0);
        acc[mt][nt] = __builtin_amdgcn_mfma_f32_16x16x32_bf16(af[mt][1], bfr[nt][1], acc[mt][nt], 0, 0, 0);
      }
  }

  const int mbase = m0 + wm * 64 + quad * 4;
  const int nbase = n0 + wn * 64 + l16;
  const bool fold = (kc == 0);
  float bv[4];
#pragma unroll
  for (int nt = 0; nt < 4; nt++) bv[nt] = fold ? bias[nbase + nt * 16] : 0.f;
#pragma unroll
  for (int mt = 0; mt < 4; mt++) {
#pragma unroll
    for (int r = 0; r < 4; r++) {
      const int m = mbase + mt * 16 + r;
#pragma unroll
      for (int nt = 0; nt < 4; nt++) {
        const int n = nbase + nt * 16;
        float val = acc[mt][nt][r] + bv[nt];
        if (fold) val += res[(size_t)m * N + n];
        atomicAdd(&C[(size_t)m * N + n], val);
      }
    }
  }
}

// ---------------- Flash attention, transposed form (S^T / O^T) ----------------
__global__ __launch_bounds__(256) void attn_mfma(const bf16* __restrict__ qkv,
                                                 const bf16* __restrict__ vT,
                                                 bf16* __restrict__ y) {
  const int qt = blockIdx.x, h = blockIdx.y, b = blockIdx.z;
  const int tid  = threadIdx.x;
  const int wave = tid >> 6, lane = tid & 63;
  const int quad = lane >> 4, l16 = lane & 15;
  const int sw8  = l16 & 7;

  __shared__ __align__(16) bf16 Ks[64 * 64];
  __shared__ __align__(16) bf16 Vs[64 * 64];
  __shared__ __align__(16) bf16 Ps[4][16 * 64];

  const size_t base = (size_t)b * SEQ * 3072;
  const int q0 = qt * 64 + wave * 16;

  const bf16* qrow = qkv + base + (size_t)(q0 + l16) * 3072 + h * HDIM;
  short8 qb0 = *(const short8*)(qrow + quad * 8);
  short8 qb1 = *(const short8*)(qrow + 32 + quad * 8);
  {
    bf16* p0 = (bf16*)&qb0; bf16* p1 = (bf16*)&qb1;
#pragma unroll
    for (int j = 0; j < 8; j++) {
      p0[j] = __float2bfloat16(__bfloat162float(p0[j]) * 0.125f);
      p1[j] = __float2bfloat16(__bfloat162float(p1[j]) * 0.125f);
    }
  }

  floatx4 O[4];
#pragma unroll
  for (int c = 0; c < 4; c++) O[c] = (floatx4){0.f, 0.f, 0.f, 0.f};
  float lsum = 0.f;

  const int skey = tid >> 3, sc = tid & 7;
  const int gcol = (sc ^ (skey & 7)) * 8;
  const bf16* kg = qkv + base + D_MODEL + h * HDIM;
  const bf16* vg = vT + (size_t)(h * HDIM) * (size_t)ROWS + b * SEQ;

  for (int kt = 0; kt < SEQ; kt += 64) {
    __syncthreads();
    load_lds16(kg + (size_t)(kt + skey) * 3072 + gcol,      &Ks[tid * 8]);
    load_lds16(kg + (size_t)(kt + skey + 32) * 3072 + gcol, &Ks[(tid + 256) * 8]);
    load_lds16(vg + (size_t)skey * ROWS + kt + gcol,        &Vs[tid * 8]);
    load_lds16(vg + (size_t)(skey + 32) * ROWS + kt + gcol, &Vs[(tid + 256) * 8]);
    __syncthreads();

    floatx4 S[4];
#pragma unroll
    for (int g = 0; g < 4; g++) {
      S[g] = (floatx4){0.f, 0.f, 0.f, 0.f};
      const short8 ka0 = *(const short8*)&Ks[(g * 16 + l16) * 64 + ((quad    ) ^ sw8) * 8];
      const short8 ka1 = *(const short8*)&Ks[(g * 16 + l16) * 64 + ((quad + 4) ^ sw8) * 8];
      S[g] = __builtin_amdgcn_mfma_f32_16x16x32_bf16(ka0, qb0, S[g], 0, 0, 0);
      S[g] = __builtin_amdgcn_mfma_f32_16x16x32_bf16(ka1, qb1, S[g], 0, 0, 0);
    }

#pragma unroll
    for (int g = 0; g < 4; g++) {
      float p[4];
#pragma unroll
      for (int r = 0; r < 4; r++) { p[r] = __expf(S[g][r]); lsum += p[r]; }
      bf16 pb[4];
#pragma unroll
      for (int r = 0; r < 4; r++) pb[r] = __float2bfloat16(p[r]);
      const int chunk = 2 * g + (quad >> 1);
      *(short4v*)&Ps[wave][l16 * 64 + (chunk ^ sw8) * 8 + (quad & 1) * 4] =
          *(const short4v*)pb;
    }

    const short8 pb0 = *(const short8*)&Ps[wave][l16 * 64 + ((quad    ) ^ sw8) * 8];
    const short8 pb1 = *(const short8*)&Ps[wave][l16 * 64 + ((quad + 4) ^ sw8) * 8];
#pragma unroll
    for (int c = 0; c < 4; c++) {
      const short8 va0 = *(const short8*)&Vs[(c * 16 + l16) * 64 + ((quad    ) ^ sw8) * 8];
      const short8 va1 = *(const short8*)&Vs[(c * 16 + l16) * 64 + ((quad + 4) ^ sw8) * 8];
      O[c] = __builtin_amdgcn_mfma_f32_16x16x32_bf16(va0, pb0, O[c], 0, 0, 0);
      O[c] = __builtin_amdgcn_mfma_f32_16x16x32_bf16(va1, pb1, O[c], 0, 0, 0);
    }
  }

  lsum += __shfl_xor(lsum, 16);
  lsum += __shfl_xor(lsum, 32);
  const float inv = 1.0f / lsum;

  bf16* yrow = y + (size_t)(b * SEQ + q0 + l16) * D_MODEL + h * HDIM + quad * 4;
#pragma unroll
  for (int c = 0; c < 4; c++) {
    bf16 ov[4];
#pragma unroll
    for (int r = 0; r < 4; r++) ov[r] = __float2bfloat16(O[c][r] * inv);
    *(short4v*)(yrow + c * 16) = *(const short4v*)ov;
  }
}

extern "C" void kernel_launch(void* const* d_in, const int* in_sizes, int n_in,
                              void* d_out, int out_size, void* d_ws, size_t ws_size,
                              hipStream_t stream) {
  const float* x      = (const float*)d_in[0];
  const float* ln1_g  = (const float*)d_in[1];
  const float* ln1_b  = (const float*)d_in[2];
  const float* ln2_g  = (const float*)d_in[3];
  const float* ln2_b  = (const float*)d_in[4];
  const float* w_qkv  = (const float*)d_in[5];
  const float* b_qkv  = (const float*)d_in[6];
  const float* w_proj = (const float*)d_in[7];
  const float* b_proj = (const float*)d_in[8];
  const float* w_fc1  = (const float*)d_in[9];
  const float* b_fc1  = (const float*)d_in[10];
  const float* w_fc2  = (const float*)d_in[11];
  const float* b_fc2  = (const float*)d_in[12];
  float* out = (float*)d_out;

  // Workspace map (88 MiB high-water):
  //   [ 0, 8M)  h        [ 8,32M) qkv      [ 8,16M) wt_fc1 (post-attn)
  //   [16,24M)  wt_fc2 (post-attn)          [32,40M) y
  //   [40,56M)  x1 (f32) [56,88M) ffh      [56,62M) wt_qkv  [62,64M) wt_proj
  //   [64,72M)  vT (dead before ffh written)
  char* ws = (char*)d_ws;
  bf16*  h       = (bf16*)(ws);
  bf16*  qkv     = (bf16*)(ws + (8u  << 20));
  bf16*  wt_fc1  = (bf16*)(ws + (8u  << 20));
  bf16*  wt_fc2  = (bf16*)(ws + (16u << 20));
  bf16*  y       = (bf16*)(ws + (32u << 20));
  float* x1      = (float*)(ws + (40u << 20));
  bf16*  ffh     = (bf16*)(ws + (56u << 20));
  bf16*  wt_qkv  = (bf16*)(ws + (56u << 20));
  bf16*  wt_proj = (bf16*)(ws + (62u << 20));
  bf16*  vT      = (bf16*)(ws + (64u << 20));

  // zero split-K accumulation targets (graph-capturable)
  hipMemsetAsync(x1,  0, (size_t)ROWS * D_MODEL * 4, stream);
  hipMemsetAsync(out, 0, (size_t)ROWS * D_MODEL * 4, stream);

  convert_w<<<dim3(3072 / 64, 1024 / 64), 256, 0, stream>>>(w_qkv, wt_qkv, 1024, 3072);
  convert_w<<<dim3(1024 / 64, 1024 / 64), 256, 0, stream>>>(w_proj, wt_proj, 1024, 1024);
  // 1. h = LN1(x)
  ln_kernel<float><<<ROWS, 256, 0, stream>>>(x, ln1_g, ln1_b, h);
  // 2. qkv = h @ w_qkv + b_qkv
  gemm_mfma<0, bf16><<<dim3(3072 / 128, ROWS / 128), 256, 0, stream>>>(
      h, wt_qkv, b_qkv, qkv, ROWS, 3072, D_MODEL);
  // 2b. vT = V^T
  v_transpose<<<dim3(ROWS / 64, 1024 / 64), 256, 0, stream>>>(qkv, vT);
  // 3. y = softmax(q k^T / 8) v
  attn_mfma<<<dim3(SEQ / 64, NHEAD, BATCH), 256, 0, stream>>>(qkv, vT, y);
  convert_w<<<dim3(4096 / 64, 1024 / 64), 256, 0, stream>>>(w_fc1, wt_fc1, 1024, 4096);
  convert_w<<<dim3(1024 / 64, 4096 / 64), 256, 0, stream>>>(w_fc2, wt_fc2, 4096, 1024);
  // 4. x1 = x + y @ w_proj + b_proj   (split-K 2-way, atomic f32)
  gemm_mfma_sk<<<dim3(1024 / 128, ROWS / 128, 2), 256, 0, stream>>>(
      y, wt_proj, b_proj, x, x1, ROWS, D_MODEL, D_MODEL, 512);
  // 5. h = LN2(x1)
  ln_kernel<float><<<ROWS, 256, 0, stream>>>(x1, ln2_g, ln2_b, h);
  // 6. ffh = gelu(h @ w_fc1 + b_fc1)
  gemm_mfma<1, bf16><<<dim3(4096 / 128, ROWS / 128), 256, 0, stream>>>(
      h, wt_fc1, b_fc1, ffh, ROWS, FFDIM, D_MODEL);
  // 7. out = x1 + ffh @ w_fc2 + b_fc2   (split-K 4-way, atomic f32)
  gemm_mfma_sk<<<dim3(1024 / 128, ROWS / 128, 4), 256, 0, stream>>>(
      ffh, wt_fc2, b_fc2, x1, out, ROWS, D_MODEL, FFDIM, 1024);
}

// Round 7
// 380.501 us; speedup vs baseline: 1.1312x; 1.1312x over previous
//
#include <hip/hip_runtime.h>
#include <hip/hip_bf16.h>
#include <math.h>

typedef __hip_bfloat16 bf16;
typedef __attribute__((ext_vector_type(8))) short short8;
typedef __attribute__((ext_vector_type(4))) short short4v;
typedef __attribute__((ext_vector_type(4))) float floatx4;

#define D_MODEL 1024
#define SEQ     2048
#define BATCH   2
#define NHEAD   16
#define HDIM    64
#define FFDIM   4096
#define ROWS    (BATCH*SEQ)   // 4096 token rows

__device__ __forceinline__ void stv(bf16* p, float v)  { *p = __float2bfloat16(v); }
__device__ __forceinline__ void stv(float* p, float v) { *p = v; }

__device__ __forceinline__ void load_lds16(const bf16* g, bf16* l) {
  __builtin_amdgcn_global_load_lds((const __attribute__((address_space(1))) void*)g,
                                   (__attribute__((address_space(3))) void*)l, 16, 0, 0);
}

// ---------------- LayerNorm: one 256-thread block per row of 1024 ----------------
template<typename IN_T>
__global__ void ln_kernel(const IN_T* __restrict__ x, const float* __restrict__ g,
                          const float* __restrict__ beta, bf16* __restrict__ out) {
  const int row = blockIdx.x;
  const int tid = threadIdx.x;
  __shared__ float red[8];
  const IN_T* xr = x + (size_t)row * D_MODEL;
  float v[4], s = 0.f, ss = 0.f;
#pragma unroll
  for (int i = 0; i < 4; i++) {
    float val = (float)xr[tid + i * 256];
    v[i] = val; s += val; ss += val * val;
  }
#pragma unroll
  for (int off = 32; off > 0; off >>= 1) {
    s  += __shfl_down(s, off);
    ss += __shfl_down(ss, off);
  }
  if ((tid & 63) == 0) { red[tid >> 6] = s; red[4 + (tid >> 6)] = ss; }
  __syncthreads();
  s  = red[0] + red[1] + red[2] + red[3];
  ss = red[4] + red[5] + red[6] + red[7];
  const float mu  = s * (1.0f / D_MODEL);
  const float var = ss * (1.0f / D_MODEL) - mu * mu;
  const float rs  = rsqrtf(var + 1e-5f);
  bf16* orow = out + (size_t)row * D_MODEL;
#pragma unroll
  for (int i = 0; i < 4; i++) {
    int c = tid + i * 256;
    stv(orow + c, (v[i] - mu) * rs * g[c] + beta[c]);
  }
}

// ---------------- W[K][N] f32 -> Wt[N][K] bf16 (transpose + cast) ----------------
__global__ __launch_bounds__(256) void convert_w(const float* __restrict__ W,
                                                 bf16* __restrict__ Wt, int K, int N) {
  __shared__ float tile[64][65];
  const int n0 = blockIdx.x * 64, k0 = blockIdx.y * 64;
  const int tid = threadIdx.x;
  const int r = tid >> 2, c0 = (tid & 3) * 16;
#pragma unroll
  for (int j = 0; j < 16; j += 4) {
    float4 v = *(const float4*)&W[(size_t)(k0 + r) * N + n0 + c0 + j];
    tile[r][c0 + j]     = v.x; tile[r][c0 + j + 1] = v.y;
    tile[r][c0 + j + 2] = v.z; tile[r][c0 + j + 3] = v.w;
  }
  __syncthreads();
  bf16 ov[16];
#pragma unroll
  for (int j = 0; j < 16; j++) ov[j] = __float2bfloat16(tile[c0 + j][r]);
  *(short8*)&Wt[(size_t)(n0 + r) * K + k0 + c0]     = *(const short8*)&ov[0];
  *(short8*)&Wt[(size_t)(n0 + r) * K + k0 + c0 + 8] = *(const short8*)&ov[8];
}

// ------------- V-transpose: vT[h*64+d][b*2048+t] = qkv[b*2048+t][2048+h*64+d] ----
__global__ __launch_bounds__(256) void v_transpose(const bf16* __restrict__ qkv,
                                                   bf16* __restrict__ vT) {
  __shared__ bf16 tile[64][72];
  const int m0 = blockIdx.x * 64;
  const int d0 = blockIdx.y * 64;
  const int tid = threadIdx.x;
  const int r = tid >> 2, c0 = (tid & 3) * 16;
  *(short8*)&tile[r][c0]     = *(const short8*)&qkv[(size_t)(m0 + r) * 3072 + 2048 + d0 + c0];
  *(short8*)&tile[r][c0 + 8] = *(const short8*)&qkv[(size_t)(m0 + r) * 3072 + 2048 + d0 + c0 + 8];
  __syncthreads();
  bf16 ov[16];
#pragma unroll
  for (int j = 0; j < 16; j++) ov[j] = tile[c0 + j][r];
  *(short8*)&vT[(size_t)(d0 + r) * (size_t)ROWS + m0 + c0]     = *(const short8*)&ov[0];
  *(short8*)&vT[(size_t)(d0 + r) * (size_t)ROWS + m0 + c0 + 8] = *(const short8*)&ov[8];
}

// ------- MFMA GEMM: C[M,N] = act(A[M,K] @ Bt[N,K]^T + bias) (+res), tile 128xTN --
// TN=128: 4 waves as 2x2 of 64x64 (4x4 MFMA tiles/wave).
// TN=64:  4 waves as 4x1 of 32x64 (2x4 MFMA tiles/wave) — for narrow-N GEMMs,
//         doubles grid size (latency hiding) without extra output traffic.
template<int ACT, bool HAS_RES, int TN, typename OUT_T>
__global__ __launch_bounds__(256) void gemm_mfma(
    const bf16* __restrict__ A, const bf16* __restrict__ Bt,
    const float* __restrict__ bias, const float* __restrict__ res,
    OUT_T* __restrict__ C, int M, int N, int K) {
  constexpr int MT = (TN == 128) ? 4 : 2;           // m 16-tiles per wave
  __shared__ __align__(16) bf16 As[128][64];
  __shared__ __align__(16) bf16 Bs[TN][64];
  const int tid = threadIdx.x;
  const int w = tid >> 6, lane = tid & 63;
  const int quad = lane >> 4, l16 = lane & 15;
  const int wm = (TN == 128) ? (w >> 1) : w;
  const int wn = (TN == 128) ? (w & 1) : 0;
  const int wave_m_off = wm * ((TN == 128) ? 64 : 32);
  const int m0 = blockIdx.y * 128, n0 = blockIdx.x * TN;
  const int rb = lane >> 3, cb = lane & 7;
  const int csw = cb ^ rb;

  const bf16* Ag = A  + (size_t)(m0 + w * 8 + rb) * K + csw * 8;
  const bf16* Bg = Bt + (size_t)(n0 + w * 8 + rb) * K + csw * 8;

  floatx4 acc[MT][4];
#pragma unroll
  for (int i = 0; i < MT; i++)
#pragma unroll
    for (int j = 0; j < 4; j++) acc[i][j] = (floatx4){0.f, 0.f, 0.f, 0.f};

  const int sw = l16 & 7;
  for (int k0 = 0; k0 < K; k0 += 64) {
    __syncthreads();
#pragma unroll
    for (int j = 0; j < 4; j++)
      load_lds16(Ag + k0 + (size_t)j * 32 * K, &As[j * 32 + w * 8][0]);
#pragma unroll
    for (int j = 0; j < TN / 32; j++)
      load_lds16(Bg + k0 + (size_t)j * 32 * K, &Bs[j * 32 + w * 8][0]);
    __syncthreads();
    short8 af[MT][2], bfr[4][2];
#pragma unroll
    for (int t = 0; t < MT; t++)
#pragma unroll
      for (int hh = 0; hh < 2; hh++) {
        int cc = ((quad + hh * 4) ^ sw) * 8;
        af[t][hh] = *(const short8*)&As[wave_m_off + t * 16 + l16][cc];
      }
#pragma unroll
    for (int t = 0; t < 4; t++)
#pragma unroll
      for (int hh = 0; hh < 2; hh++) {
        int cc = ((quad + hh * 4) ^ sw) * 8;
        bfr[t][hh] = *(const short8*)&Bs[wn * 64 + t * 16 + l16][cc];
      }
#pragma unroll
    for (int mt = 0; mt < MT; mt++)
#pragma unroll
      for (int nt = 0; nt < 4; nt++) {
        acc[mt][nt] = __builtin_amdgcn_mfma_f32_16x16x32_bf16(af[mt][0], bfr[nt][0], acc[mt][nt], 0, 0, 0);
        acc[mt][nt] = __builtin_amdgcn_mfma_f32_16x16x32_bf16(af[mt][1], bfr[nt][1], acc[mt][nt], 0, 0, 0);
      }
  }

  const int mbase = m0 + wave_m_off + quad * 4;
  const int nbase = n0 + wn * 64 + l16;
  float bv[4];
#pragma unroll
  for (int nt = 0; nt < 4; nt++) bv[nt] = bias[nbase + nt * 16];
#pragma unroll
  for (int mt = 0; mt < MT; mt++) {
#pragma unroll
    for (int r = 0; r < 4; r++) {
      const int m = mbase + mt * 16 + r;
#pragma unroll
      for (int nt = 0; nt < 4; nt++) {
        const int n = nbase + nt * 16;
        float val = acc[mt][nt][r] + bv[nt];
        if (ACT == 1) val = 0.5f * val * (1.0f + erff(val * 0.70710678118f));
        if (HAS_RES) val += res[(size_t)m * N + n];
        stv(&C[(size_t)m * N + n], val);
      }
    }
  }
}

// ---------------- Flash attention, transposed form (S^T / O^T) ----------------
__global__ __launch_bounds__(256) void attn_mfma(const bf16* __restrict__ qkv,
                                                 const bf16* __restrict__ vT,
                                                 bf16* __restrict__ y) {
  const int qt = blockIdx.x, h = blockIdx.y, b = blockIdx.z;
  const int tid  = threadIdx.x;
  const int wave = tid >> 6, lane = tid & 63;
  const int quad = lane >> 4, l16 = lane & 15;
  const int sw8  = l16 & 7;

  __shared__ __align__(16) bf16 Ks[64 * 64];
  __shared__ __align__(16) bf16 Vs[64 * 64];
  __shared__ __align__(16) bf16 Ps[4][16 * 64];

  const size_t base = (size_t)b * SEQ * 3072;
  const int q0 = qt * 64 + wave * 16;

  const bf16* qrow = qkv + base + (size_t)(q0 + l16) * 3072 + h * HDIM;
  short8 qb0 = *(const short8*)(qrow + quad * 8);
  short8 qb1 = *(const short8*)(qrow + 32 + quad * 8);
  {
    bf16* p0 = (bf16*)&qb0; bf16* p1 = (bf16*)&qb1;
#pragma unroll
    for (int j = 0; j < 8; j++) {
      p0[j] = __float2bfloat16(__bfloat162float(p0[j]) * 0.125f);
      p1[j] = __float2bfloat16(__bfloat162float(p1[j]) * 0.125f);
    }
  }

  floatx4 O[4];
#pragma unroll
  for (int c = 0; c < 4; c++) O[c] = (floatx4){0.f, 0.f, 0.f, 0.f};
  float lsum = 0.f;

  const int skey = tid >> 3, sc = tid & 7;
  const int gcol = (sc ^ (skey & 7)) * 8;
  const bf16* kg = qkv + base + D_MODEL + h * HDIM;
  const bf16* vg = vT + (size_t)(h * HDIM) * (size_t)ROWS + b * SEQ;

  for (int kt = 0; kt < SEQ; kt += 64) {
    __syncthreads();
    load_lds16(kg + (size_t)(kt + skey) * 3072 + gcol,      &Ks[tid * 8]);
    load_lds16(kg + (size_t)(kt + skey + 32) * 3072 + gcol, &Ks[(tid + 256) * 8]);
    load_lds16(vg + (size_t)skey * ROWS + kt + gcol,        &Vs[tid * 8]);
    load_lds16(vg + (size_t)(skey + 32) * ROWS + kt + gcol, &Vs[(tid + 256) * 8]);
    __syncthreads();

    floatx4 S[4];
#pragma unroll
    for (int g = 0; g < 4; g++) {
      S[g] = (floatx4){0.f, 0.f, 0.f, 0.f};
      const short8 ka0 = *(const short8*)&Ks[(g * 16 + l16) * 64 + ((quad    ) ^ sw8) * 8];
      const short8 ka1 = *(const short8*)&Ks[(g * 16 + l16) * 64 + ((quad + 4) ^ sw8) * 8];
      S[g] = __builtin_amdgcn_mfma_f32_16x16x32_bf16(ka0, qb0, S[g], 0, 0, 0);
      S[g] = __builtin_amdgcn_mfma_f32_16x16x32_bf16(ka1, qb1, S[g], 0, 0, 0);
    }

#pragma unroll
    for (int g = 0; g < 4; g++) {
      float p[4];
#pragma unroll
      for (int r = 0; r < 4; r++) { p[r] = __expf(S[g][r]); lsum += p[r]; }
      bf16 pb[4];
#pragma unroll
      for (int r = 0; r < 4; r++) pb[r] = __float2bfloat16(p[r]);
      const int chunk = 2 * g + (quad >> 1);
      *(short4v*)&Ps[wave][l16 * 64 + (chunk ^ sw8) * 8 + (quad & 1) * 4] =
          *(const short4v*)pb;
    }

    const short8 pb0 = *(const short8*)&Ps[wave][l16 * 64 + ((quad    ) ^ sw8) * 8];
    const short8 pb1 = *(const short8*)&Ps[wave][l16 * 64 + ((quad + 4) ^ sw8) * 8];
#pragma unroll
    for (int c = 0; c < 4; c++) {
      const short8 va0 = *(const short8*)&Vs[(c * 16 + l16) * 64 + ((quad    ) ^ sw8) * 8];
      const short8 va1 = *(const short8*)&Vs[(c * 16 + l16) * 64 + ((quad + 4) ^ sw8) * 8];
      O[c] = __builtin_amdgcn_mfma_f32_16x16x32_bf16(va0, pb0, O[c], 0, 0, 0);
      O[c] = __builtin_amdgcn_mfma_f32_16x16x32_bf16(va1, pb1, O[c], 0, 0, 0);
    }
  }

  lsum += __shfl_xor(lsum, 16);
  lsum += __shfl_xor(lsum, 32);
  const float inv = 1.0f / lsum;

  bf16* yrow = y + (size_t)(b * SEQ + q0 + l16) * D_MODEL + h * HDIM + quad * 4;
#pragma unroll
  for (int c = 0; c < 4; c++) {
    bf16 ov[4];
#pragma unroll
    for (int r = 0; r < 4; r++) ov[r] = __float2bfloat16(O[c][r] * inv);
    *(short4v*)(yrow + c * 16) = *(const short4v*)ov;
  }
}

extern "C" void kernel_launch(void* const* d_in, const int* in_sizes, int n_in,
                              void* d_out, int out_size, void* d_ws, size_t ws_size,
                              hipStream_t stream) {
  const float* x      = (const float*)d_in[0];
  const float* ln1_g  = (const float*)d_in[1];
  const float* ln1_b  = (const float*)d_in[2];
  const float* ln2_g  = (const float*)d_in[3];
  const float* ln2_b  = (const float*)d_in[4];
  const float* w_qkv  = (const float*)d_in[5];
  const float* b_qkv  = (const float*)d_in[6];
  const float* w_proj = (const float*)d_in[7];
  const float* b_proj = (const float*)d_in[8];
  const float* w_fc1  = (const float*)d_in[9];
  const float* b_fc1  = (const float*)d_in[10];
  const float* w_fc2  = (const float*)d_in[11];
  const float* b_fc2  = (const float*)d_in[12];
  float* out = (float*)d_out;

  // Workspace map (88 MiB high-water):
  //   [ 0, 8M)  h        [ 8,32M) qkv      [ 8,16M) wt_fc1 (post-attn)
  //   [16,24M)  wt_fc2 (post-attn)          [32,40M) y
  //   [40,56M)  x1 (f32) [56,88M) ffh      [56,62M) wt_qkv  [62,64M) wt_proj
  //   [64,72M)  vT (dead before ffh written)
  char* ws = (char*)d_ws;
  bf16*  h       = (bf16*)(ws);
  bf16*  qkv     = (bf16*)(ws + (8u  << 20));
  bf16*  wt_fc1  = (bf16*)(ws + (8u  << 20));
  bf16*  wt_fc2  = (bf16*)(ws + (16u << 20));
  bf16*  y       = (bf16*)(ws + (32u << 20));
  float* x1      = (float*)(ws + (40u << 20));
  bf16*  ffh     = (bf16*)(ws + (56u << 20));
  bf16*  wt_qkv  = (bf16*)(ws + (56u << 20));
  bf16*  wt_proj = (bf16*)(ws + (62u << 20));
  bf16*  vT      = (bf16*)(ws + (64u << 20));

  convert_w<<<dim3(3072 / 64, 1024 / 64), 256, 0, stream>>>(w_qkv, wt_qkv, 1024, 3072);
  convert_w<<<dim3(1024 / 64, 1024 / 64), 256, 0, stream>>>(w_proj, wt_proj, 1024, 1024);
  // 1. h = LN1(x)
  ln_kernel<float><<<ROWS, 256, 0, stream>>>(x, ln1_g, ln1_b, h);
  // 2. qkv = h @ w_qkv + b_qkv
  gemm_mfma<0, false, 128, bf16><<<dim3(3072 / 128, ROWS / 128), 256, 0, stream>>>(
      h, wt_qkv, b_qkv, nullptr, qkv, ROWS, 3072, D_MODEL);
  // 2b. vT = V^T
  v_transpose<<<dim3(ROWS / 64, 1024 / 64), 256, 0, stream>>>(qkv, vT);
  // 3. y = softmax(q k^T / 8) v
  attn_mfma<<<dim3(SEQ / 64, NHEAD, BATCH), 256, 0, stream>>>(qkv, vT, y);
  convert_w<<<dim3(4096 / 64, 1024 / 64), 256, 0, stream>>>(w_fc1, wt_fc1, 1024, 4096);
  convert_w<<<dim3(1024 / 64, 4096 / 64), 256, 0, stream>>>(w_fc2, wt_fc2, 4096, 1024);
  // 4. x1 = x + y @ w_proj + b_proj   (narrow-N: 128x64 tiles, 512 blocks)
  gemm_mfma<0, true, 64, float><<<dim3(1024 / 64, ROWS / 128), 256, 0, stream>>>(
      y, wt_proj, b_proj, x, x1, ROWS, D_MODEL, D_MODEL);
  // 5. h = LN2(x1)
  ln_kernel<float><<<ROWS, 256, 0, stream>>>(x1, ln2_g, ln2_b, h);
  // 6. ffh = gelu(h @ w_fc1 + b_fc1)
  gemm_mfma<1, false, 128, bf16><<<dim3(4096 / 128, ROWS / 128), 256, 0, stream>>>(
      h, wt_fc1, b_fc1, nullptr, ffh, ROWS, FFDIM, D_MODEL);
  // 7. out = x1 + ffh @ w_fc2 + b_fc2   (narrow-N: 128x64 tiles, 512 blocks)
  gemm_mfma<0, true, 64, float><<<dim3(1024 / 64, ROWS / 128), 256, 0, stream>>>(
      ffh, wt_fc2, b_fc2, x1, out, ROWS, D_MODEL, FFDIM);
}

// Round 8
// 361.757 us; speedup vs baseline: 1.1898x; 1.0518x over previous
//
#include <hip/hip_runtime.h>
#include <hip/hip_bf16.h>
#include <math.h>

typedef __hip_bfloat16 bf16;
typedef __attribute__((ext_vector_type(8))) short short8;
typedef __attribute__((ext_vector_type(4))) short short4v;
typedef __attribute__((ext_vector_type(4))) float floatx4;

#define D_MODEL 1024
#define SEQ     2048
#define BATCH   2
#define NHEAD   16
#define HDIM    64
#define FFDIM   4096
#define ROWS    (BATCH*SEQ)   // 4096 token rows

__device__ __forceinline__ void stv(bf16* p, float v)  { *p = __float2bfloat16(v); }
__device__ __forceinline__ void stv(float* p, float v) { *p = v; }

__device__ __forceinline__ void load_lds16(const bf16* g, bf16* l) {
  __builtin_amdgcn_global_load_lds((const __attribute__((address_space(1))) void*)g,
                                   (__attribute__((address_space(3))) void*)l, 16, 0, 0);
}

// fast GELU: x * sigmoid(x*(c0 + c1*x^2)) == tanh-form GELU; max |err| vs exact ~4e-4
__device__ __forceinline__ float gelu_fast(float x) {
  float z = x * (1.5957691f + 0.07135481f * x * x);
  return x * __builtin_amdgcn_rcpf(1.0f + __expf(-z));
}

// ---------------- LayerNorm: one 256-thread block per row of 1024 ----------------
template<typename IN_T>
__global__ void ln_kernel(const IN_T* __restrict__ x, const float* __restrict__ g,
                          const float* __restrict__ beta, bf16* __restrict__ out) {
  const int row = blockIdx.x;
  const int tid = threadIdx.x;
  __shared__ float red[8];
  const IN_T* xr = x + (size_t)row * D_MODEL;
  float v[4], s = 0.f, ss = 0.f;
#pragma unroll
  for (int i = 0; i < 4; i++) {
    float val = (float)xr[tid + i * 256];
    v[i] = val; s += val; ss += val * val;
  }
#pragma unroll
  for (int off = 32; off > 0; off >>= 1) {
    s  += __shfl_down(s, off);
    ss += __shfl_down(ss, off);
  }
  if ((tid & 63) == 0) { red[tid >> 6] = s; red[4 + (tid >> 6)] = ss; }
  __syncthreads();
  s  = red[0] + red[1] + red[2] + red[3];
  ss = red[4] + red[5] + red[6] + red[7];
  const float mu  = s * (1.0f / D_MODEL);
  const float var = ss * (1.0f / D_MODEL) - mu * mu;
  const float rs  = rsqrtf(var + 1e-5f);
  bf16* orow = out + (size_t)row * D_MODEL;
#pragma unroll
  for (int i = 0; i < 4; i++) {
    int c = tid + i * 256;
    stv(orow + c, (v[i] - mu) * rs * g[c] + beta[c]);
  }
}

// -------- W[K][N] f32 -> Wt[N][K] bf16, two jobs batched in one dispatch --------
__device__ __forceinline__ void convert_tile(const float* W, bf16* Wt,
                                             int K, int N, int n0, int k0, int tid) {
  __shared__ float tile[64][65];
  const int r = tid >> 2, c0 = (tid & 3) * 16;
#pragma unroll
  for (int j = 0; j < 16; j += 4) {
    float4 v = *(const float4*)&W[(size_t)(k0 + r) * N + n0 + c0 + j];
    tile[r][c0 + j]     = v.x; tile[r][c0 + j + 1] = v.y;
    tile[r][c0 + j + 2] = v.z; tile[r][c0 + j + 3] = v.w;
  }
  __syncthreads();
  bf16 ov[16];
#pragma unroll
  for (int j = 0; j < 16; j++) ov[j] = __float2bfloat16(tile[c0 + j][r]);
  *(short8*)&Wt[(size_t)(n0 + r) * K + k0 + c0]     = *(const short8*)&ov[0];
  *(short8*)&Wt[(size_t)(n0 + r) * K + k0 + c0 + 8] = *(const short8*)&ov[8];
}

__global__ __launch_bounds__(256) void convert_w2(
    const float* __restrict__ W0, bf16* __restrict__ Wt0, int K0, int N0, int tiles0,
    const float* __restrict__ W1, bf16* __restrict__ Wt1, int K1, int N1) {
  int bid = blockIdx.x;
  const int tid = threadIdx.x;
  if (bid < tiles0) {
    const int nt = N0 >> 6;
    convert_tile(W0, Wt0, K0, N0, (bid % nt) * 64, (bid / nt) * 64, tid);
  } else {
    bid -= tiles0;
    const int nt = N1 >> 6;
    convert_tile(W1, Wt1, K1, N1, (bid % nt) * 64, (bid / nt) * 64, tid);
  }
}

// ------------- V-transpose: vT[h*64+d][b*2048+t] = qkv[b*2048+t][2048+h*64+d] ----
__global__ __launch_bounds__(256) void v_transpose(const bf16* __restrict__ qkv,
                                                   bf16* __restrict__ vT) {
  __shared__ bf16 tile[64][72];
  const int m0 = blockIdx.x * 64;
  const int d0 = blockIdx.y * 64;
  const int tid = threadIdx.x;
  const int r = tid >> 2, c0 = (tid & 3) * 16;
  *(short8*)&tile[r][c0]     = *(const short8*)&qkv[(size_t)(m0 + r) * 3072 + 2048 + d0 + c0];
  *(short8*)&tile[r][c0 + 8] = *(const short8*)&qkv[(size_t)(m0 + r) * 3072 + 2048 + d0 + c0 + 8];
  __syncthreads();
  bf16 ov[16];
#pragma unroll
  for (int j = 0; j < 16; j++) ov[j] = tile[c0 + j][r];
  *(short8*)&vT[(size_t)(d0 + r) * (size_t)ROWS + m0 + c0]     = *(const short8*)&ov[0];
  *(short8*)&vT[(size_t)(d0 + r) * (size_t)ROWS + m0 + c0 + 8] = *(const short8*)&ov[8];
}

// ------- MFMA GEMM: C[M,N] = act(A[M,K] @ Bt[N,K]^T + bias) (+res), tile 128xTN --
template<int ACT, bool HAS_RES, int TN, typename OUT_T>
__global__ __launch_bounds__(256) void gemm_mfma(
    const bf16* __restrict__ A, const bf16* __restrict__ Bt,
    const float* __restrict__ bias, const float* __restrict__ res,
    OUT_T* __restrict__ C, int M, int N, int K) {
  constexpr int MT = (TN == 128) ? 4 : 2;
  __shared__ __align__(16) bf16 As[128][64];
  __shared__ __align__(16) bf16 Bs[TN][64];
  const int tid = threadIdx.x;
  const int w = tid >> 6, lane = tid & 63;
  const int quad = lane >> 4, l16 = lane & 15;
  const int wm = (TN == 128) ? (w >> 1) : w;
  const int wn = (TN == 128) ? (w & 1) : 0;
  const int wave_m_off = wm * ((TN == 128) ? 64 : 32);
  const int m0 = blockIdx.y * 128, n0 = blockIdx.x * TN;
  const int rb = lane >> 3, cb = lane & 7;
  const int csw = cb ^ rb;

  const bf16* Ag = A  + (size_t)(m0 + w * 8 + rb) * K + csw * 8;
  const bf16* Bg = Bt + (size_t)(n0 + w * 8 + rb) * K + csw * 8;

  floatx4 acc[MT][4];
#pragma unroll
  for (int i = 0; i < MT; i++)
#pragma unroll
    for (int j = 0; j < 4; j++) acc[i][j] = (floatx4){0.f, 0.f, 0.f, 0.f};

  const int sw = l16 & 7;
  for (int k0 = 0; k0 < K; k0 += 64) {
    __syncthreads();
#pragma unroll
    for (int j = 0; j < 4; j++)
      load_lds16(Ag + k0 + (size_t)j * 32 * K, &As[j * 32 + w * 8][0]);
#pragma unroll
    for (int j = 0; j < TN / 32; j++)
      load_lds16(Bg + k0 + (size_t)j * 32 * K, &Bs[j * 32 + w * 8][0]);
    __syncthreads();
    short8 af[MT][2], bfr[4][2];
#pragma unroll
    for (int t = 0; t < MT; t++)
#pragma unroll
      for (int hh = 0; hh < 2; hh++) {
        int cc = ((quad + hh * 4) ^ sw) * 8;
        af[t][hh] = *(const short8*)&As[wave_m_off + t * 16 + l16][cc];
      }
#pragma unroll
    for (int t = 0; t < 4; t++)
#pragma unroll
      for (int hh = 0; hh < 2; hh++) {
        int cc = ((quad + hh * 4) ^ sw) * 8;
        bfr[t][hh] = *(const short8*)&Bs[wn * 64 + t * 16 + l16][cc];
      }
#pragma unroll
    for (int mt = 0; mt < MT; mt++)
#pragma unroll
      for (int nt = 0; nt < 4; nt++) {
        acc[mt][nt] = __builtin_amdgcn_mfma_f32_16x16x32_bf16(af[mt][0], bfr[nt][0], acc[mt][nt], 0, 0, 0);
        acc[mt][nt] = __builtin_amdgcn_mfma_f32_16x16x32_bf16(af[mt][1], bfr[nt][1], acc[mt][nt], 0, 0, 0);
      }
  }

  const int mbase = m0 + wave_m_off + quad * 4;
  const int nbase = n0 + wn * 64 + l16;
  float bv[4];
#pragma unroll
  for (int nt = 0; nt < 4; nt++) bv[nt] = bias[nbase + nt * 16];
#pragma unroll
  for (int mt = 0; mt < MT; mt++) {
#pragma unroll
    for (int r = 0; r < 4; r++) {
      const int m = mbase + mt * 16 + r;
#pragma unroll
      for (int nt = 0; nt < 4; nt++) {
        const int n = nbase + nt * 16;
        float val = acc[mt][nt][r] + bv[nt];
        if (ACT == 1) val = gelu_fast(val);
        if (HAS_RES) val += res[(size_t)m * N + n];
        stv(&C[(size_t)m * N + n], val);
      }
    }
  }
}

// ---------------- Flash attention, transposed form (S^T / O^T) ----------------
__global__ __launch_bounds__(256) void attn_mfma(const bf16* __restrict__ qkv,
                                                 const bf16* __restrict__ vT,
                                                 bf16* __restrict__ y) {
  const int qt = blockIdx.x, h = blockIdx.y, b = blockIdx.z;
  const int tid  = threadIdx.x;
  const int wave = tid >> 6, lane = tid & 63;
  const int quad = lane >> 4, l16 = lane & 15;
  const int sw8  = l16 & 7;

  __shared__ __align__(16) bf16 Ks[64 * 64];
  __shared__ __align__(16) bf16 Vs[64 * 64];
  __shared__ __align__(16) bf16 Ps[4][16 * 64];

  const size_t base = (size_t)b * SEQ * 3072;
  const int q0 = qt * 64 + wave * 16;

  const bf16* qrow = qkv + base + (size_t)(q0 + l16) * 3072 + h * HDIM;
  short8 qb0 = *(const short8*)(qrow + quad * 8);
  short8 qb1 = *(const short8*)(qrow + 32 + quad * 8);
  {
    bf16* p0 = (bf16*)&qb0; bf16* p1 = (bf16*)&qb1;
#pragma unroll
    for (int j = 0; j < 8; j++) {
      p0[j] = __float2bfloat16(__bfloat162float(p0[j]) * 0.125f);
      p1[j] = __float2bfloat16(__bfloat162float(p1[j]) * 0.125f);
    }
  }

  floatx4 O[4];
#pragma unroll
  for (int c = 0; c < 4; c++) O[c] = (floatx4){0.f, 0.f, 0.f, 0.f};
  float lsum = 0.f;

  const int skey = tid >> 3, sc = tid & 7;
  const int gcol = (sc ^ (skey & 7)) * 8;
  const bf16* kg = qkv + base + D_MODEL + h * HDIM;
  const bf16* vg = vT + (size_t)(h * HDIM) * (size_t)ROWS + b * SEQ;

  for (int kt = 0; kt < SEQ; kt += 64) {
    __syncthreads();
    load_lds16(kg + (size_t)(kt + skey) * 3072 + gcol,      &Ks[tid * 8]);
    load_lds16(kg + (size_t)(kt + skey + 32) * 3072 + gcol, &Ks[(tid + 256) * 8]);
    load_lds16(vg + (size_t)skey * ROWS + kt + gcol,        &Vs[tid * 8]);
    load_lds16(vg + (size_t)(skey + 32) * ROWS + kt + gcol, &Vs[(tid + 256) * 8]);
    __syncthreads();

    floatx4 S[4];
#pragma unroll
    for (int g = 0; g < 4; g++) {
      S[g] = (floatx4){0.f, 0.f, 0.f, 0.f};
      const short8 ka0 = *(const short8*)&Ks[(g * 16 + l16) * 64 + ((quad    ) ^ sw8) * 8];
      const short8 ka1 = *(const short8*)&Ks[(g * 16 + l16) * 64 + ((quad + 4) ^ sw8) * 8];
      S[g] = __builtin_amdgcn_mfma_f32_16x16x32_bf16(ka0, qb0, S[g], 0, 0, 0);
      S[g] = __builtin_amdgcn_mfma_f32_16x16x32_bf16(ka1, qb1, S[g], 0, 0, 0);
    }

#pragma unroll
    for (int g = 0; g < 4; g++) {
      float p[4];
#pragma unroll
      for (int r = 0; r < 4; r++) { p[r] = __expf(S[g][r]); lsum += p[r]; }
      bf16 pb[4];
#pragma unroll
      for (int r = 0; r < 4; r++) pb[r] = __float2bfloat16(p[r]);
      const int chunk = 2 * g + (quad >> 1);
      *(short4v*)&Ps[wave][l16 * 64 + (chunk ^ sw8) * 8 + (quad & 1) * 4] =
          *(const short4v*)pb;
    }

    const short8 pb0 = *(const short8*)&Ps[wave][l16 * 64 + ((quad    ) ^ sw8) * 8];
    const short8 pb1 = *(const short8*)&Ps[wave][l16 * 64 + ((quad + 4) ^ sw8) * 8];
#pragma unroll
    for (int c = 0; c < 4; c++) {
      const short8 va0 = *(const short8*)&Vs[(c * 16 + l16) * 64 + ((quad    ) ^ sw8) * 8];
      const short8 va1 = *(const short8*)&Vs[(c * 16 + l16) * 64 + ((quad + 4) ^ sw8) * 8];
      O[c] = __builtin_amdgcn_mfma_f32_16x16x32_bf16(va0, pb0, O[c], 0, 0, 0);
      O[c] = __builtin_amdgcn_mfma_f32_16x16x32_bf16(va1, pb1, O[c], 0, 0, 0);
    }
  }

  lsum += __shfl_xor(lsum, 16);
  lsum += __shfl_xor(lsum, 32);
  const float inv = 1.0f / lsum;

  bf16* yrow = y + (size_t)(b * SEQ + q0 + l16) * D_MODEL + h * HDIM + quad * 4;
#pragma unroll
  for (int c = 0; c < 4; c++) {
    bf16 ov[4];
#pragma unroll
    for (int r = 0; r < 4; r++) ov[r] = __float2bfloat16(O[c][r] * inv);
    *(short4v*)(yrow + c * 16) = *(const short4v*)ov;
  }
}

extern "C" void kernel_launch(void* const* d_in, const int* in_sizes, int n_in,
                              void* d_out, int out_size, void* d_ws, size_t ws_size,
                              hipStream_t stream) {
  const float* x      = (const float*)d_in[0];
  const float* ln1_g  = (const float*)d_in[1];
  const float* ln1_b  = (const float*)d_in[2];
  const float* ln2_g  = (const float*)d_in[3];
  const float* ln2_b  = (const float*)d_in[4];
  const float* w_qkv  = (const float*)d_in[5];
  const float* b_qkv  = (const float*)d_in[6];
  const float* w_proj = (const float*)d_in[7];
  const float* b_proj = (const float*)d_in[8];
  const float* w_fc1  = (const float*)d_in[9];
  const float* b_fc1  = (const float*)d_in[10];
  const float* w_fc2  = (const float*)d_in[11];
  const float* b_fc2  = (const float*)d_in[12];
  float* out = (float*)d_out;

  // Workspace map (88 MiB high-water):
  //   [ 0, 8M)  h        [ 8,32M) qkv      [ 8,16M) wt_fc1 (post-attn)
  //   [16,24M)  wt_fc2 (post-attn)          [32,40M) y
  //   [40,56M)  x1 (f32) [56,88M) ffh      [56,62M) wt_qkv  [62,64M) wt_proj
  //   [64,72M)  vT (dead before ffh written)
  char* ws = (char*)d_ws;
  bf16*  h       = (bf16*)(ws);
  bf16*  qkv     = (bf16*)(ws + (8u  << 20));
  bf16*  wt_fc1  = (bf16*)(ws + (8u  << 20));
  bf16*  wt_fc2  = (bf16*)(ws + (16u << 20));
  bf16*  y       = (bf16*)(ws + (32u << 20));
  float* x1      = (float*)(ws + (40u << 20));
  bf16*  ffh     = (bf16*)(ws + (56u << 20));
  bf16*  wt_qkv  = (bf16*)(ws + (56u << 20));
  bf16*  wt_proj = (bf16*)(ws + (62u << 20));
  bf16*  vT      = (bf16*)(ws + (64u << 20));

  // qkv + proj weight converts (one dispatch)
  convert_w2<<<768 + 256, 256, 0, stream>>>(w_qkv, wt_qkv, 1024, 3072, 768,
                                            w_proj, wt_proj, 1024, 1024);
  // 1. h = LN1(x)
  ln_kernel<float><<<ROWS, 256, 0, stream>>>(x, ln1_g, ln1_b, h);
  // 2. qkv = h @ w_qkv + b_qkv
  gemm_mfma<0, false, 128, bf16><<<dim3(3072 / 128, ROWS / 128), 256, 0, stream>>>(
      h, wt_qkv, b_qkv, nullptr, qkv, ROWS, 3072, D_MODEL);
  // 2b. vT = V^T
  v_transpose<<<dim3(ROWS / 64, 1024 / 64), 256, 0, stream>>>(qkv, vT);
  // 3. y = softmax(q k^T / 8) v
  attn_mfma<<<dim3(SEQ / 64, NHEAD, BATCH), 256, 0, stream>>>(qkv, vT, y);
  // fc1 + fc2 weight converts (one dispatch; must follow attn: overlays qkv)
  convert_w2<<<1024 + 1024, 256, 0, stream>>>(w_fc1, wt_fc1, 1024, 4096, 1024,
                                              w_fc2, wt_fc2, 4096, 1024);
  // 4. x1 = x + y @ w_proj + b_proj   (narrow-N: 128x64 tiles)
  gemm_mfma<0, true, 64, float><<<dim3(1024 / 64, ROWS / 128), 256, 0, stream>>>(
      y, wt_proj, b_proj, x, x1, ROWS, D_MODEL, D_MODEL);
  // 5. h = LN2(x1)
  ln_kernel<float><<<ROWS, 256, 0, stream>>>(x1, ln2_g, ln2_b, h);
  // 6. ffh = gelu(h @ w_fc1 + b_fc1)
  gemm_mfma<1, false, 128, bf16><<<dim3(4096 / 128, ROWS / 128), 256, 0, stream>>>(
      h, wt_fc1, b_fc1, nullptr, ffh, ROWS, FFDIM, D_MODEL);
  // 7. out = x1 + ffh @ w_fc2 + b_fc2   (narrow-N: 128x64 tiles)
  gemm_mfma<0, true, 64, float><<<dim3(1024 / 64, ROWS / 128), 256, 0, stream>>>(
      ffh, wt_fc2, b_fc2, x1, out, ROWS, D_MODEL, FFDIM);
}

// Round 9
// 345.834 us; speedup vs baseline: 1.2446x; 1.0460x over previous
//
#include <hip/hip_runtime.h>
#include <hip/hip_bf16.h>
#include <math.h>

typedef __hip_bfloat16 bf16;
typedef __attribute__((ext_vector_type(8))) short short8;
typedef __attribute__((ext_vector_type(4))) short short4v;
typedef __attribute__((ext_vector_type(4))) float floatx4;

#define D_MODEL 1024
#define SEQ     2048
#define BATCH   2
#define NHEAD   16
#define HDIM    64
#define FFDIM   4096
#define ROWS    (BATCH*SEQ)   // 4096 token rows

__device__ __forceinline__ void stv(bf16* p, float v)  { *p = __float2bfloat16(v); }
__device__ __forceinline__ void stv(float* p, float v) { *p = v; }

__device__ __forceinline__ void load_lds16(const bf16* g, bf16* l) {
  __builtin_amdgcn_global_load_lds((const __attribute__((address_space(1))) void*)g,
                                   (__attribute__((address_space(3))) void*)l, 16, 0, 0);
}

// fast GELU: x * sigmoid(x*(c0 + c1*x^2)) == tanh-form GELU; max |err| vs exact ~4e-4
__device__ __forceinline__ float gelu_fast(float x) {
  float z = x * (1.5957691f + 0.07135481f * x * x);
  return x * __builtin_amdgcn_rcpf(1.0f + __expf(-z));
}

// ---------------- LayerNorm: one 256-thread block per row of 1024 ----------------
template<typename IN_T>
__global__ void ln_kernel(const IN_T* __restrict__ x, const float* __restrict__ g,
                          const float* __restrict__ beta, bf16* __restrict__ out) {
  const int row = blockIdx.x;
  const int tid = threadIdx.x;
  __shared__ float red[8];
  const IN_T* xr = x + (size_t)row * D_MODEL;
  float v[4], s = 0.f, ss = 0.f;
#pragma unroll
  for (int i = 0; i < 4; i++) {
    float val = (float)xr[tid + i * 256];
    v[i] = val; s += val; ss += val * val;
  }
#pragma unroll
  for (int off = 32; off > 0; off >>= 1) {
    s  += __shfl_down(s, off);
    ss += __shfl_down(ss, off);
  }
  if ((tid & 63) == 0) { red[tid >> 6] = s; red[4 + (tid >> 6)] = ss; }
  __syncthreads();
  s  = red[0] + red[1] + red[2] + red[3];
  ss = red[4] + red[5] + red[6] + red[7];
  const float mu  = s * (1.0f / D_MODEL);
  const float var = ss * (1.0f / D_MODEL) - mu * mu;
  const float rs  = rsqrtf(var + 1e-5f);
  bf16* orow = out + (size_t)row * D_MODEL;
#pragma unroll
  for (int i = 0; i < 4; i++) {
    int c = tid + i * 256;
    stv(orow + c, (v[i] - mu) * rs * g[c] + beta[c]);
  }
}

// -------- W[K][N] f32 -> Wt[N][K] bf16, two jobs batched in one dispatch --------
__device__ __forceinline__ void convert_tile(const float* W, bf16* Wt,
                                             int K, int N, int n0, int k0, int tid) {
  __shared__ float tile[64][65];
  const int r = tid >> 2, c0 = (tid & 3) * 16;
#pragma unroll
  for (int j = 0; j < 16; j += 4) {
    float4 v = *(const float4*)&W[(size_t)(k0 + r) * N + n0 + c0 + j];
    tile[r][c0 + j]     = v.x; tile[r][c0 + j + 1] = v.y;
    tile[r][c0 + j + 2] = v.z; tile[r][c0 + j + 3] = v.w;
  }
  __syncthreads();
  bf16 ov[16];
#pragma unroll
  for (int j = 0; j < 16; j++) ov[j] = __float2bfloat16(tile[c0 + j][r]);
  *(short8*)&Wt[(size_t)(n0 + r) * K + k0 + c0]     = *(const short8*)&ov[0];
  *(short8*)&Wt[(size_t)(n0 + r) * K + k0 + c0 + 8] = *(const short8*)&ov[8];
}

__global__ __launch_bounds__(256) void convert_w2(
    const float* __restrict__ W0, bf16* __restrict__ Wt0, int K0, int N0, int tiles0,
    const float* __restrict__ W1, bf16* __restrict__ Wt1, int K1, int N1) {
  int bid = blockIdx.x;
  const int tid = threadIdx.x;
  if (bid < tiles0) {
    const int nt = N0 >> 6;
    convert_tile(W0, Wt0, K0, N0, (bid % nt) * 64, (bid / nt) * 64, tid);
  } else {
    bid -= tiles0;
    const int nt = N1 >> 6;
    convert_tile(W1, Wt1, K1, N1, (bid % nt) * 64, (bid / nt) * 64, tid);
  }
}

// ------------- V-transpose: vT[h*64+d][b*2048+t] = qkv[b*2048+t][2048+h*64+d] ----
__global__ __launch_bounds__(256) void v_transpose(const bf16* __restrict__ qkv,
                                                   bf16* __restrict__ vT) {
  __shared__ bf16 tile[64][72];
  const int m0 = blockIdx.x * 64;
  const int d0 = blockIdx.y * 64;
  const int tid = threadIdx.x;
  const int r = tid >> 2, c0 = (tid & 3) * 16;
  *(short8*)&tile[r][c0]     = *(const short8*)&qkv[(size_t)(m0 + r) * 3072 + 2048 + d0 + c0];
  *(short8*)&tile[r][c0 + 8] = *(const short8*)&qkv[(size_t)(m0 + r) * 3072 + 2048 + d0 + c0 + 8];
  __syncthreads();
  bf16 ov[16];
#pragma unroll
  for (int j = 0; j < 16; j++) ov[j] = tile[c0 + j][r];
  *(short8*)&vT[(size_t)(d0 + r) * (size_t)ROWS + m0 + c0]     = *(const short8*)&ov[0];
  *(short8*)&vT[(size_t)(d0 + r) * (size_t)ROWS + m0 + c0 + 8] = *(const short8*)&ov[8];
}

// ------- MFMA GEMM: C[M,N] = act(A[M,K] @ Bt[N,K]^T + bias) (+res), tile TMxTN --
// 1D grid, XCD-clustered swizzle: blocks sharing an A-panel (same m) land on the
// same XCD (assumes round-robin bid%8 -> XCD; perf heuristic only).
// (TM,TN)=(128,128): 4 waves 2x2 of 64x64, MT=4.  (128,64): 4x1 waves, MT=2.
// (64,64): 4 waves of 16 rows, MT=1 (narrow-N: 4 blocks/CU for latency hiding).
template<int ACT, bool HAS_RES, int TM, int TN, typename OUT_T>
__global__ __launch_bounds__(256) void gemm_mfma(
    const bf16* __restrict__ A, const bf16* __restrict__ Bt,
    const float* __restrict__ bias, const float* __restrict__ res,
    OUT_T* __restrict__ C, int M, int N, int K, int NTI) {
  constexpr int MT = (TN == 128) ? 4 : (TM == 128 ? 2 : 1);
  __shared__ __align__(16) bf16 As[TM][64];
  __shared__ __align__(16) bf16 Bs[TN][64];
  const int tid = threadIdx.x;
  const int w = tid >> 6, lane = tid & 63;
  const int quad = lane >> 4, l16 = lane & 15;
  const int wm = (TN == 128) ? (w >> 1) : w;
  const int wn = (TN == 128) ? (w & 1) : 0;
  const int wave_m_off = wm * (MT * 16);
  // XCD-clustered decode: m-groups of 8 interleave across XCD slots
  const int bid = blockIdx.x;
  const int n_idx = (bid >> 3) % NTI;
  const int m_idx = ((bid >> 3) / NTI) * 8 + (bid & 7);
  const int m0 = m_idx * TM, n0 = n_idx * TN;
  const int rb = lane >> 3, cb = lane & 7;
  const int csw = cb ^ rb;

  const bf16* Ag = A  + (size_t)(m0 + (tid >> 3)) * K + csw * 8;
  const bf16* Bg = Bt + (size_t)(n0 + (tid >> 3)) * K + csw * 8;

  floatx4 acc[MT][4];
#pragma unroll
  for (int i = 0; i < MT; i++)
#pragma unroll
    for (int j = 0; j < 4; j++) acc[i][j] = (floatx4){0.f, 0.f, 0.f, 0.f};

  const int sw = l16 & 7;
  for (int k0 = 0; k0 < K; k0 += 64) {
    __syncthreads();
#pragma unroll
    for (int j = 0; j < TM / 32; j++)
      load_lds16(Ag + k0 + (size_t)j * 32 * K, &As[j * 32 + (tid >> 3)][0]);
#pragma unroll
    for (int j = 0; j < TN / 32; j++)
      load_lds16(Bg + k0 + (size_t)j * 32 * K, &Bs[j * 32 + (tid >> 3)][0]);
    __syncthreads();
    short8 af[MT][2], bfr[4][2];
#pragma unroll
    for (int t = 0; t < MT; t++)
#pragma unroll
      for (int hh = 0; hh < 2; hh++) {
        int cc = ((quad + hh * 4) ^ sw) * 8;
        af[t][hh] = *(const short8*)&As[wave_m_off + t * 16 + l16][cc];
      }
#pragma unroll
    for (int t = 0; t < 4; t++)
#pragma unroll
      for (int hh = 0; hh < 2; hh++) {
        int cc = ((quad + hh * 4) ^ sw) * 8;
        bfr[t][hh] = *(const short8*)&Bs[wn * 64 + t * 16 + l16][cc];
      }
#pragma unroll
    for (int mt = 0; mt < MT; mt++)
#pragma unroll
      for (int nt = 0; nt < 4; nt++) {
        acc[mt][nt] = __builtin_amdgcn_mfma_f32_16x16x32_bf16(af[mt][0], bfr[nt][0], acc[mt][nt], 0, 0, 0);
        acc[mt][nt] = __builtin_amdgcn_mfma_f32_16x16x32_bf16(af[mt][1], bfr[nt][1], acc[mt][nt], 0, 0, 0);
      }
  }

  const int mbase = m0 + wave_m_off + quad * 4;
  const int nbase = n0 + wn * 64 + l16;
  float bv[4];
#pragma unroll
  for (int nt = 0; nt < 4; nt++) bv[nt] = bias[nbase + nt * 16];
#pragma unroll
  for (int mt = 0; mt < MT; mt++) {
#pragma unroll
    for (int r = 0; r < 4; r++) {
      const int m = mbase + mt * 16 + r;
#pragma unroll
      for (int nt = 0; nt < 4; nt++) {
        const int n = nbase + nt * 16;
        float val = acc[mt][nt][r] + bv[nt];
        if (ACT == 1) val = gelu_fast(val);
        if (HAS_RES) val += res[(size_t)m * N + n];
        stv(&C[(size_t)m * N + n], val);
      }
    }
  }
}

// ---------------- Flash attention, transposed form (S^T / O^T) ----------------
__global__ __launch_bounds__(256) void attn_mfma(const bf16* __restrict__ qkv,
                                                 const bf16* __restrict__ vT,
                                                 bf16* __restrict__ y) {
  const int qt = blockIdx.x, h = blockIdx.y, b = blockIdx.z;
  const int tid  = threadIdx.x;
  const int wave = tid >> 6, lane = tid & 63;
  const int quad = lane >> 4, l16 = lane & 15;
  const int sw8  = l16 & 7;

  __shared__ __align__(16) bf16 Ks[64 * 64];
  __shared__ __align__(16) bf16 Vs[64 * 64];
  __shared__ __align__(16) bf16 Ps[4][16 * 64];

  const size_t base = (size_t)b * SEQ * 3072;
  const int q0 = qt * 64 + wave * 16;

  const bf16* qrow = qkv + base + (size_t)(q0 + l16) * 3072 + h * HDIM;
  short8 qb0 = *(const short8*)(qrow + quad * 8);
  short8 qb1 = *(const short8*)(qrow + 32 + quad * 8);
  {
    bf16* p0 = (bf16*)&qb0; bf16* p1 = (bf16*)&qb1;
#pragma unroll
    for (int j = 0; j < 8; j++) {
      p0[j] = __float2bfloat16(__bfloat162float(p0[j]) * 0.125f);
      p1[j] = __float2bfloat16(__bfloat162float(p1[j]) * 0.125f);
    }
  }

  floatx4 O[4];
#pragma unroll
  for (int c = 0; c < 4; c++) O[c] = (floatx4){0.f, 0.f, 0.f, 0.f};
  float lsum = 0.f;

  const int skey = tid >> 3, sc = tid & 7;
  const int gcol = (sc ^ (skey & 7)) * 8;
  const bf16* kg = qkv + base + D_MODEL + h * HDIM;
  const bf16* vg = vT + (size_t)(h * HDIM) * (size_t)ROWS + b * SEQ;

  for (int kt = 0; kt < SEQ; kt += 64) {
    __syncthreads();
    load_lds16(kg + (size_t)(kt + skey) * 3072 + gcol,      &Ks[tid * 8]);
    load_lds16(kg + (size_t)(kt + skey + 32) * 3072 + gcol, &Ks[(tid + 256) * 8]);
    load_lds16(vg + (size_t)skey * ROWS + kt + gcol,        &Vs[tid * 8]);
    load_lds16(vg + (size_t)(skey + 32) * ROWS + kt + gcol, &Vs[(tid + 256) * 8]);
    __syncthreads();

    floatx4 S[4];
#pragma unroll
    for (int g = 0; g < 4; g++) {
      S[g] = (floatx4){0.f, 0.f, 0.f, 0.f};
      const short8 ka0 = *(const short8*)&Ks[(g * 16 + l16) * 64 + ((quad    ) ^ sw8) * 8];
      const short8 ka1 = *(const short8*)&Ks[(g * 16 + l16) * 64 + ((quad + 4) ^ sw8) * 8];
      S[g] = __builtin_amdgcn_mfma_f32_16x16x32_bf16(ka0, qb0, S[g], 0, 0, 0);
      S[g] = __builtin_amdgcn_mfma_f32_16x16x32_bf16(ka1, qb1, S[g], 0, 0, 0);
    }

#pragma unroll
    for (int g = 0; g < 4; g++) {
      float p[4];
#pragma unroll
      for (int r = 0; r < 4; r++) { p[r] = __expf(S[g][r]); lsum += p[r]; }
      bf16 pb[4];
#pragma unroll
      for (int r = 0; r < 4; r++) pb[r] = __float2bfloat16(p[r]);
      const int chunk = 2 * g + (quad >> 1);
      *(short4v*)&Ps[wave][l16 * 64 + (chunk ^ sw8) * 8 + (quad & 1) * 4] =
          *(const short4v*)pb;
    }

    const short8 pb0 = *(const short8*)&Ps[wave][l16 * 64 + ((quad    ) ^ sw8) * 8];
    const short8 pb1 = *(const short8*)&Ps[wave][l16 * 64 + ((quad + 4) ^ sw8) * 8];
#pragma unroll
    for (int c = 0; c < 4; c++) {
      const short8 va0 = *(const short8*)&Vs[(c * 16 + l16) * 64 + ((quad    ) ^ sw8) * 8];
      const short8 va1 = *(const short8*)&Vs[(c * 16 + l16) * 64 + ((quad + 4) ^ sw8) * 8];
      O[c] = __builtin_amdgcn_mfma_f32_16x16x32_bf16(va0, pb0, O[c], 0, 0, 0);
      O[c] = __builtin_amdgcn_mfma_f32_16x16x32_bf16(va1, pb1, O[c], 0, 0, 0);
    }
  }

  lsum += __shfl_xor(lsum, 16);
  lsum += __shfl_xor(lsum, 32);
  const float inv = 1.0f / lsum;

  bf16* yrow = y + (size_t)(b * SEQ + q0 + l16) * D_MODEL + h * HDIM + quad * 4;
#pragma unroll
  for (int c = 0; c < 4; c++) {
    bf16 ov[4];
#pragma unroll
    for (int r = 0; r < 4; r++) ov[r] = __float2bfloat16(O[c][r] * inv);
    *(short4v*)(yrow + c * 16) = *(const short4v*)ov;
  }
}

extern "C" void kernel_launch(void* const* d_in, const int* in_sizes, int n_in,
                              void* d_out, int out_size, void* d_ws, size_t ws_size,
                              hipStream_t stream) {
  const float* x      = (const float*)d_in[0];
  const float* ln1_g  = (const float*)d_in[1];
  const float* ln1_b  = (const float*)d_in[2];
  const float* ln2_g  = (const float*)d_in[3];
  const float* ln2_b  = (const float*)d_in[4];
  const float* w_qkv  = (const float*)d_in[5];
  const float* b_qkv  = (const float*)d_in[6];
  const float* w_proj = (const float*)d_in[7];
  const float* b_proj = (const float*)d_in[8];
  const float* w_fc1  = (const float*)d_in[9];
  const float* b_fc1  = (const float*)d_in[10];
  const float* w_fc2  = (const float*)d_in[11];
  const float* b_fc2  = (const float*)d_in[12];
  float* out = (float*)d_out;

  // Workspace map (88 MiB high-water):
  //   [ 0, 8M)  h        [ 8,32M) qkv      [ 8,16M) wt_fc1 (post-attn)
  //   [16,24M)  wt_fc2 (post-attn)          [32,40M) y
  //   [40,56M)  x1 (f32) [56,88M) ffh      [56,62M) wt_qkv  [62,64M) wt_proj
  //   [64,72M)  vT (dead before ffh written)
  char* ws = (char*)d_ws;
  bf16*  h       = (bf16*)(ws);
  bf16*  qkv     = (bf16*)(ws + (8u  << 20));
  bf16*  wt_fc1  = (bf16*)(ws + (8u  << 20));
  bf16*  wt_fc2  = (bf16*)(ws + (16u << 20));
  bf16*  y       = (bf16*)(ws + (32u << 20));
  float* x1      = (float*)(ws + (40u << 20));
  bf16*  ffh     = (bf16*)(ws + (56u << 20));
  bf16*  wt_qkv  = (bf16*)(ws + (56u << 20));
  bf16*  wt_proj = (bf16*)(ws + (62u << 20));
  bf16*  vT      = (bf16*)(ws + (64u << 20));

  // qkv + proj weight converts (one dispatch)
  convert_w2<<<768 + 256, 256, 0, stream>>>(w_qkv, wt_qkv, 1024, 3072, 768,
                                            w_proj, wt_proj, 1024, 1024);
  // 1. h = LN1(x)
  ln_kernel<float><<<ROWS, 256, 0, stream>>>(x, ln1_g, ln1_b, h);
  // 2. qkv = h @ w_qkv + b_qkv   (128x128, 24x32=768 blocks, XCD-swizzled)
  gemm_mfma<0, false, 128, 128, bf16><<<768, 256, 0, stream>>>(
      h, wt_qkv, b_qkv, nullptr, qkv, ROWS, 3072, D_MODEL, 24);
  // 2b. vT = V^T
  v_transpose<<<dim3(ROWS / 64, 1024 / 64), 256, 0, stream>>>(qkv, vT);
  // 3. y = softmax(q k^T / 8) v
  attn_mfma<<<dim3(SEQ / 64, NHEAD, BATCH), 256, 0, stream>>>(qkv, vT, y);
  // fc1 + fc2 weight converts (one dispatch; must follow attn: overlays qkv)
  convert_w2<<<1024 + 1024, 256, 0, stream>>>(w_fc1, wt_fc1, 1024, 4096, 1024,
                                              w_fc2, wt_fc2, 4096, 1024);
  // 4. x1 = x + y @ w_proj + b_proj   (64x64 tiles, 16x64=1024 blocks)
  gemm_mfma<0, true, 64, 64, float><<<1024, 256, 0, stream>>>(
      y, wt_proj, b_proj, x, x1, ROWS, D_MODEL, D_MODEL, 16);
  // 5. h = LN2(x1)
  ln_kernel<float><<<ROWS, 256, 0, stream>>>(x1, ln2_g, ln2_b, h);
  // 6. ffh = gelu(h @ w_fc1 + b_fc1)   (128x128, 32x32=1024 blocks)
  gemm_mfma<1, false, 128, 128, bf16><<<1024, 256, 0, stream>>>(
      h, wt_fc1, b_fc1, nullptr, ffh, ROWS, FFDIM, D_MODEL, 32);
  // 7. out = x1 + ffh @ w_fc2 + b_fc2   (64x64 tiles, 16x64=1024 blocks)
  gemm_mfma<0, true, 64, 64, float><<<1024, 256, 0, stream>>>(
      ffh, wt_fc2, b_fc2, x1, out, ROWS, D_MODEL, FFDIM, 16);
}